// Round 10
// baseline (415.563 us; speedup 1.0000x reference)
//
#include <hip/hip_runtime.h>
#include <hip/hip_bf16.h>
#include <cstdint>
#include <cstddef>

#define D 128
#define NWG 200        // workgroups for edge binning passes

typedef _Float16 f16;
typedef f16 f16x2 __attribute__((ext_vector_type(2)));
typedef f16 f16x4 __attribute__((ext_vector_type(4)));
typedef f16 f16x8 __attribute__((ext_vector_type(8)));
typedef float f32x4 __attribute__((ext_vector_type(4)));
typedef unsigned short u16;

static inline size_t align256(size_t x){ return (x + 255) & ~(size_t)255; }

// Inline int64-vs-int32 edge dtype probe: odd dwords of int64 data are all 0.
__device__ __forceinline__ int detect_is64(const void* ei){
  const int* e32 = (const int*)ei;
  int probe = e32[2 * (threadIdx.x & 31) + 1];
  return (__ballot(probe != 0) == 0ULL) ? 1 : 0;
}

__device__ __forceinline__ void load_edge(const void* ei, int E, int is64, int e, int& s, int& d){
  if (is64) {
    const long long* p = (const long long*)ei;
    s = (int)p[e]; d = (int)p[(size_t)E + e];
  } else {
    const int* p = (const int*)ei;
    s = p[e]; d = p[(size_t)E + e];
  }
}

// ---------------------------------------------------------------------------
// Pass A: per-(bucket, wg) histogram via LDS counters. No global atomics.
__global__ __launch_bounds__(256) void passA_hist(
    const void* __restrict__ ei, int E,
    int* __restrict__ glob_hist, int NB){
  __shared__ int cnt[256];
  int t = threadIdx.x, wg = blockIdx.x;
  int is64 = detect_is64(ei);
  cnt[t] = 0;
  __syncthreads();
  int chunk = (E + NWG - 1) / NWG;
  int lo = wg * chunk, hi = min(lo + chunk, E);
  for (int e = lo + t; e < hi; e += 256){
    int s, d;
    load_edge(ei, E, is64, e, s, d);
    atomicAdd(&cnt[d >> 8], 1);
  }
  __syncthreads();
  for (int b = t; b < NB; b += 256)
    glob_hist[b * NWG + wg] = cnt[b];
}

// ---------- generic exclusive scan (partial + blocksums; add folded into readers) ----------
__global__ void scan_partial(const int* __restrict__ src, int* __restrict__ dst,
                             int* __restrict__ blockSums, int L){
  __shared__ int sd[256];
  int t = threadIdx.x;
  int base = blockIdx.x * 1024 + t * 4;
  int v[4]; int s = 0;
  #pragma unroll
  for (int j = 0; j < 4; ++j){ v[j] = (base + j < L) ? src[base + j] : 0; s += v[j]; }
  sd[t] = s; __syncthreads();
  for (int off = 1; off < 256; off <<= 1){
    int x = (t >= off) ? sd[t - off] : 0;
    __syncthreads();
    sd[t] += x;
    __syncthreads();
  }
  int run = sd[t] - s;
  #pragma unroll
  for (int j = 0; j < 4; ++j){
    if (base + j < L) dst[base + j] = run;
    run += v[j];
  }
  if (t == 255) blockSums[blockIdx.x] = sd[255];
}

__global__ void scan_blocksums(int* __restrict__ blockSums, int nblk){
  __shared__ int sd[256];
  int t = threadIdx.x;
  int v = (t < nblk) ? blockSums[t] : 0;
  sd[t] = v; __syncthreads();
  for (int off = 1; off < 256; off <<= 1){
    int x = (t >= off) ? sd[t - off] : 0;
    __syncthreads();
    sd[t] += x;
    __syncthreads();
  }
  if (t < nblk) blockSums[t] = sd[t] - v;   // exclusive
}

// ---------------------------------------------------------------------------
// Pass B: scatter packed edges (src | dstLow<<16) into bucket-grouped array.
__global__ __launch_bounds__(256) void passB_scatter(
    const void* __restrict__ ei, int E,
    const int* __restrict__ bucketOff, const int* __restrict__ blockSums,
    int NB, unsigned* __restrict__ packed){
  __shared__ int cur[256];
  int t = threadIdx.x, wg = blockIdx.x;
  int is64 = detect_is64(ei);
  for (int b = t; b < NB; b += 256){
    int i = b * NWG + wg;
    cur[b] = bucketOff[i] + blockSums[i >> 10];
  }
  __syncthreads();
  int chunk = (E + NWG - 1) / NWG;
  int lo = wg * chunk, hi = min(lo + chunk, E);
  for (int e = lo + t; e < hi; e += 256){
    int s, d;
    load_edge(ei, E, is64, e, s, d);
    int pos = atomicAdd(&cur[d >> 8], 1);
    packed[pos] = (unsigned)s | ((unsigned)(d & 255) << 16);
  }
}

// ---------------------------------------------------------------------------
// Pass C: one wg per bucket. Local counts -> scan -> rowptr/dis -> csr_src(u16).
__global__ __launch_bounds__(256) void passC_csr(
    const unsigned* __restrict__ packed, const int* __restrict__ bucketOff,
    const int* __restrict__ blockSums, int NB, int N, int E,
    int* __restrict__ rowptr, float* __restrict__ dis, u16* __restrict__ csr_src){
  __shared__ int degl[256];
  __shared__ int sd[256];
  __shared__ int cur[256];
  int t = threadIdx.x, b = blockIdx.x;
  int i0 = b * NWG, i1 = (b + 1) * NWG;
  int begin = bucketOff[i0] + blockSums[i0 >> 10];
  int endb  = (b == NB - 1) ? E : (bucketOff[i1] + blockSums[i1 >> 10]);
  degl[t] = 0;
  __syncthreads();
  for (int i = begin + t; i < endb; i += 256)
    atomicAdd(&degl[(packed[i] >> 16) & 255], 1);
  __syncthreads();
  int dv = degl[t];
  sd[t] = dv; __syncthreads();
  for (int off = 1; off < 256; off <<= 1){
    int x = (t >= off) ? sd[t - off] : 0;
    __syncthreads();
    sd[t] += x;
    __syncthreads();
  }
  int localOff = sd[t] - dv;
  int v = b * 256 + t;
  if (v < N){
    rowptr[v] = begin + localOff;
    dis[v] = rsqrtf((float)(dv + 1));
  }
  if (b == NB - 1 && t == 0) rowptr[N] = E;
  cur[t] = begin + localOff;
  __syncthreads();
  for (int i = begin + t; i < endb; i += 256){
    unsigned p = packed[i];
    int pos = atomicAdd(&cur[(p >> 16) & 255], 1);
    csr_src[pos] = (u16)(p & 0xFFFFu);
  }
}

// ---------------------------------------------------------------------------
// cast + pre-scale: out[v][c] = f16(in[v][c] * dis[v])
__global__ void cast_scale(const float* __restrict__ in, const float* __restrict__ dis,
                           f16* __restrict__ out, int n4){
  int i = blockIdx.x * blockDim.x + threadIdx.x;
  if (i >= n4) return;
  float dv = dis[i >> 5];
  float4 v = ((const float4*)in)[i];
  f16x4 o; o[0]=(f16)(v.x*dv); o[1]=(f16)(v.y*dv); o[2]=(f16)(v.z*dv); o[3]=(f16)(v.w*dv);
  ((f16x4*)out)[i] = o;
}

// transpose+cast 6 weight matrices: Wt[w][n][k] = W_w[k][n], fp16
__global__ void prep_w(const float* __restrict__ Wa, const float* __restrict__ Wb,
                       const float* __restrict__ Wc, const float* __restrict__ Wd,
                       const float* __restrict__ We, const float* __restrict__ Wf,
                       f16* __restrict__ Wt){
  int i = blockIdx.x * 256 + threadIdx.x;
  int w = i >> 14, rem = i & 16383;
  int n = rem >> 7, k = rem & 127;
  const float* Wp = (w==0)?Wa:(w==1)?Wb:(w==2)?Wc:(w==3)?Wd:(w==4)?We:Wf;
  Wt[i] = (f16)Wp[k*128 + n];
}

// ---------------------------------------------------------------------------
// FUSED aggregation + MFMA GEMM:
//   g[v]   = f16( dis[v] * ( sum_{u->v} in[u] + in[v] ) )   (in registers)
//   out    = g @ W + epilogue
// Block = 512 thr = 8 waves, 128 rows; wave owns rows r0..r0+15 = its MFMA
// A-fragment rows. Lane-quad (4 lanes, hi=0..3) gathers one node; lane
// accumulates its 32 A-frag channels (hi*8 + s*32 + j) in f32: 2 edges x
// 4 x 16B loads in flight per lane. W staged to LDS at entry (swizzled);
// its loads complete under the gather. EPI as before:
//   0: f16 relu(gW+b)*dis   1: f16 reparam*dis   2: f32 relu(gW+b) -> d_out
template<int EPI>
__global__ __launch_bounds__(512) void agg_gemm(
    const f16* __restrict__ in,
    const f16* __restrict__ Wt, const float* __restrict__ bias,
    const f16* __restrict__ Wt2, const float* __restrict__ bias2,
    const float* __restrict__ eps, const float* __restrict__ dis,
    const int* __restrict__ rowptr, const u16* __restrict__ csr_src,
    f16* __restrict__ out16, float* __restrict__ outf, int N){

  extern __shared__ __align__(16) f16 Ws[];   // [128][128] (+ second matrix for EPI1)

  int t = threadIdx.x;
  int wave = t >> 6, lane = t & 63;
  int lrow = lane & 15, hi = lane >> 4;
  int r0 = blockIdx.x * 128 + wave * 16;

  // ---- stage W (quad-swizzled); global loads overlap the gather below
  {
    int r = t & 127, p = t >> 7;
    const float4* src = (const float4*)&Wt[r * 128 + p * 32];
    f16* dstrow = &Ws[r * 128];
    #pragma unroll
    for (int i = 0; i < 4; ++i){
      int q = p * 4 + i;
      *(float4*)&dstrow[(q ^ (r & 7)) * 8] = src[i];
    }
    if (EPI == 1){
      const float4* src2 = (const float4*)&Wt2[r * 128 + p * 32];
      f16* dstrow2 = &Ws[16384 + r * 128];
      #pragma unroll
      for (int i = 0; i < 4; ++i){
        int q = p * 4 + i;
        *(float4*)&dstrow2[(q ^ (r & 7)) * 8] = src2[i];
      }
    }
  }

  // ---- fused gather: node v (clamped for tail), channels hi*8 + s*32 + 0..7
  int v = min(r0 + lrow, N - 1);
  float dv = dis[v];
  int beg = rowptr[v], end = rowptr[v + 1];
  const f16* inh = in + hi * 8;

  float acc[4][8];
  {  // self loop
    const f16* vrow = &inh[(size_t)v * D];
    #pragma unroll
    for (int s = 0; s < 4; ++s){
      f16x8 h = *(const f16x8*)&vrow[s * 32];
      #pragma unroll
      for (int j = 0; j < 8; ++j) acc[s][j] = (float)h[j];
    }
  }
  int e = beg;
  for (; e + 1 < end; e += 2){
    unsigned u0 = __builtin_nontemporal_load(&csr_src[e]);
    unsigned u1 = __builtin_nontemporal_load(&csr_src[e + 1]);
    const f16* p0 = &inh[(size_t)u0 * D];
    const f16* p1 = &inh[(size_t)u1 * D];
    f16x8 h0[4], h1[4];
    #pragma unroll
    for (int s = 0; s < 4; ++s){ h0[s] = *(const f16x8*)&p0[s * 32];
                                 h1[s] = *(const f16x8*)&p1[s * 32]; }
    #pragma unroll
    for (int s = 0; s < 4; ++s)
      #pragma unroll
      for (int j = 0; j < 8; ++j)
        acc[s][j] += (float)h0[s][j] + (float)h1[s][j];
  }
  if (e < end){
    unsigned u = __builtin_nontemporal_load(&csr_src[e]);
    const f16* p0 = &inh[(size_t)u * D];
    #pragma unroll
    for (int s = 0; s < 4; ++s){
      f16x8 h = *(const f16x8*)&p0[s * 32];
      #pragma unroll
      for (int j = 0; j < 8; ++j) acc[s][j] += (float)h[j];
    }
  }

  // A fragments (same rounding as the old agg16 -> gemm path)
  f16x8 a[4];
  #pragma unroll
  for (int s = 0; s < 4; ++s)
    #pragma unroll
    for (int j = 0; j < 8; ++j) a[s][j] = (f16)(acc[s][j] * dv);

  __syncthreads();

  f32x4 c1[8] = {};
  f32x4 c2[8] = {};
  #pragma unroll
  for (int s = 0; s < 4; ++s){
    #pragma unroll
    for (int tt = 0; tt < 8; ++tt){
      int n = tt * 16 + lrow;
      int q = (s * 4 + hi) ^ (lrow & 7);
      f16x8 b = *(const f16x8*)&Ws[n * 128 + q * 8];
      c1[tt] = __builtin_amdgcn_mfma_f32_16x16x32_f16(b, a[s], c1[tt], 0, 0, 0);
      if (EPI == 1){
        f16x8 b2 = *(const f16x8*)&Ws[16384 + n * 128 + q * 8];
        c2[tt] = __builtin_amdgcn_mfma_f32_16x16x32_f16(b2, a[s], c2[tt], 0, 0, 0);
      }
    }
  }

  // ---- epilogue: lane owns row r = r0+lrow, cols n0 = tt*16 + hi*4 (+0..3)
  int r = r0 + lrow;
  if (r >= N) return;
  int cbase = hi * 4;
  #pragma unroll
  for (int tt = 0; tt < 8; ++tt){
    int n0 = tt * 16 + cbase;
    f32x4 bv = *(const f32x4*)&bias[n0];
    if (EPI == 0){
      f16x4 o;
      #pragma unroll
      for (int ii = 0; ii < 4; ++ii)
        o[ii] = (f16)(fmaxf(c1[tt][ii] + bv[ii], 0.f) * dv);
      *(f16x4*)&out16[(size_t)r * D + n0] = o;
    } else if (EPI == 1){
      f32x4 bv2 = *(const f32x4*)&bias2[n0];
      f32x4 e4  = *(const f32x4*)&eps[(size_t)r * D + n0];
      f16x4 o;
      #pragma unroll
      for (int ii = 0; ii < 4; ++ii){
        float mu = c1[tt][ii] + bv[ii];
        float ls = c2[tt][ii] + bv2[ii];
        o[ii] = (f16)((mu + e4[ii] * __expf(ls) * 0.1f) * dv);
      }
      *(f16x4*)&out16[(size_t)r * D + n0] = o;
    } else {
      f32x4 o;
      #pragma unroll
      for (int ii = 0; ii < 4; ++ii)
        o[ii] = fmaxf(c1[tt][ii] + bv[ii], 0.f);
      *(f32x4*)&outf[(size_t)r * D + n0] = o;
    }
  }
}

// ---------------------------------------------------------------------------
extern "C" void kernel_launch(void* const* d_in, const int* in_sizes, int n_in,
                              void* d_out, int out_size, void* d_ws, size_t ws_size,
                              hipStream_t stream){
  const float* x   = (const float*)d_in[0];
  const void*  ei  = d_in[1];
  const float* eps = (const float*)d_in[2];
  const float* W1  = (const float*)d_in[3];  const float* b1  = (const float*)d_in[4];
  const float* W2  = (const float*)d_in[5];  const float* b2  = (const float*)d_in[6];
  const float* Wmu = (const float*)d_in[7];  const float* bmu = (const float*)d_in[8];
  const float* Wls = (const float*)d_in[9];  const float* bls = (const float*)d_in[10];
  const float* W5  = (const float*)d_in[11]; const float* b5  = (const float*)d_in[12];
  const float* W6  = (const float*)d_in[13]; const float* b6  = (const float*)d_in[14];

  const int N = in_sizes[0] / D;
  const int E = in_sizes[1] / 2;
  const int NB = (N + 255) >> 8;
  const int L  = NB * NWG;
  float* out = (float*)d_out;

  char* ws = (char*)d_ws;
  size_t off = 0;
  auto alloc = [&](size_t bytes){ char* p = ws + off; off += align256(bytes); return p; };
  int*      glob_hist = (int*)     alloc(((size_t)L + 1) * 4);
  int*      bucketOff = (int*)     alloc(((size_t)L + 1) * 4);
  int*      blockSums = (int*)     alloc(1024);
  int*      rowptr    = (int*)     alloc(((size_t)N + 1) * 4);
  float*    dis       = (float*)   alloc((size_t)N * 4);
  unsigned* packed    = (unsigned*)alloc((size_t)E * 4);
  u16*      csr_src   = (u16*)     alloc((size_t)E * 2);
  f16*      Wt        = (f16*)     alloc((size_t)6 * 128 * 128 * 2);
  f16*      bufA      = (f16*)     alloc((size_t)N * D * 2);
  f16*      bufB      = (f16*)     alloc((size_t)N * D * 2);
  (void)ws_size; (void)n_in; (void)out_size;

  // CSR build: LDS-staged counting sort by dst bucket (no global atomics)
  passA_hist<<<NWG, 256, 0, stream>>>(ei, E, glob_hist, NB);
  int nblk = (L + 1023) / 1024;
  scan_partial<<<nblk, 256, 0, stream>>>(glob_hist, bucketOff, blockSums, L);
  scan_blocksums<<<1, 256, 0, stream>>>(blockSums, nblk);
  passB_scatter<<<NWG, 256, 0, stream>>>(ei, E, bucketOff, blockSums, NB, packed);
  passC_csr<<<NB, 256, 0, stream>>>(packed, bucketOff, blockSums, NB, N, E, rowptr, dis, csr_src);

  cast_scale<<<(N * D / 4 + 255) / 256, 256, 0, stream>>>(x, dis, bufB, N * D / 4);
  prep_w<<<(6 * 16384) / 256, 256, 0, stream>>>(W1, W2, Wmu, Wls, W5, W6, Wt);

  int grid = (N + 127) / 128;
  size_t lds1 = 128 * 128 * sizeof(f16);     // 32 KB
  size_t lds2 = 2 * 128 * 128 * sizeof(f16); // 64 KB (EPI1)

  // layer 1
  agg_gemm<0><<<grid, 512, lds1, stream>>>(bufB, Wt + 0*16384, b1, nullptr, nullptr, nullptr, dis, rowptr, csr_src, bufA, nullptr, N);
  // layer 2
  agg_gemm<0><<<grid, 512, lds1, stream>>>(bufA, Wt + 1*16384, b2, nullptr, nullptr, nullptr, dis, rowptr, csr_src, bufB, nullptr, N);
  // mu/logstd share the gather; fused reparametrization
  agg_gemm<1><<<grid, 512, lds2, stream>>>(bufB, Wt + 2*16384, bmu, Wt + 3*16384, bls, eps, dis, rowptr, csr_src, bufA, nullptr, N);
  // layer 5
  agg_gemm<0><<<grid, 512, lds1, stream>>>(bufA, Wt + 4*16384, b5, nullptr, nullptr, nullptr, dis, rowptr, csr_src, bufB, nullptr, N);
  // layer 6 -> f32 d_out
  agg_gemm<2><<<grid, 512, lds1, stream>>>(bufB, Wt + 5*16384, b6, nullptr, nullptr, nullptr, dis, rowptr, csr_src, nullptr, out, N);
}